// Round 4
// baseline (450.730 us; speedup 1.0000x reference)
//
#include <hip/hip_runtime.h>

#define N_NODES 131072
#define MAXL 4096
#define NP 8

typedef __attribute__((ext_vector_type(8))) short bf16x8;
typedef __attribute__((ext_vector_type(4))) float f32x4;

// ws float offsets
#define OFF_QW     0u          // 64*256   folded (Q@WK)/16
#define OFF_QO     16384u      // 64*256   Q@WO^T
#define OFF_WF     32768u      // 256*256  WO@WV
#define OFF_QB     98304u      // 64
#define OFF_BVO    98368u      // 256
#define OFF_STARTS 98624u      // 65 ints (padded)
#define OFF_ASUM   98752u      // 64*64
#define OFF_Q      102848u     // 64*256
#define OFF_WQT    119232u     // 256*256
#define OFF_WOT    184768u     // 256*256
#define OFF_GP     250304u     // 8 * 64 * 16384  (end = 8638912 floats = 34.6 MB)

__device__ __forceinline__ unsigned short f2bf(float f) {
  union { float f; unsigned int u; } v; v.f = f;
  unsigned int u = v.u + 0x7FFFu + ((v.u >> 16) & 1u);  // RNE
  return (unsigned short)(u >> 16);
}

// cross-lane sum over kq = lane&7.
// xor1/xor2 via DPP quad_perm (VALU pipe), xor4 via ds_swizzle (LDS pipe).
__device__ __forceinline__ float xor1_add(float v) {
  int r = __builtin_amdgcn_update_dpp(0, __float_as_int(v), 0xB1, 0xF, 0xF, true); // [1,0,3,2]
  return v + __int_as_float(r);
}
__device__ __forceinline__ float xor2_add(float v) {
  int r = __builtin_amdgcn_update_dpp(0, __float_as_int(v), 0x4E, 0xF, 0xF, true); // [2,3,0,1]
  return v + __int_as_float(r);
}
__device__ __forceinline__ float xor4_add(float v) {
  int r = __builtin_amdgcn_ds_swizzle(__float_as_int(v), 0x101F);                  // xor lane^4
  return v + __int_as_float(r);
}
__device__ __forceinline__ float kq_sum(float v) { return xor4_add(xor2_add(xor1_add(v))); }

// ---------------- setup ----------------

// transpose WQ_w (z=0) and WO_w (z=1) into WQT / WOT
__global__ __launch_bounds__(256) void k_tr(const float* __restrict__ WQ_w,
    const float* __restrict__ WO_w, float* __restrict__ WQT, float* __restrict__ WOT)
{
  __shared__ float tile[32][33];
  const float* src = blockIdx.z ? WO_w : WQ_w;
  float* dst = blockIdx.z ? WOT : WQT;
  const int bx = blockIdx.x * 32, by = blockIdx.y * 32;
  const int tx = threadIdx.x & 31, ty = threadIdx.x >> 5;
  #pragma unroll
  for (int i = 0; i < 4; ++i)
    tile[ty + 8 * i][tx] = src[(size_t)(by + ty + 8 * i) * 256 + bx + tx];
  __syncthreads();
  #pragma unroll
  for (int i = 0; i < 4; ++i)
    dst[(size_t)(bx + ty + 8 * i) * 256 + by + tx] = tile[tx][ty + 8 * i];
}

// Q[c][d] = sum_k Qp[c][k] * WQT[k][d] + WQ_b[d]   (K split over 4 groups)
__global__ __launch_bounds__(1024) void k_q(const float* __restrict__ Qp,
    const float* __restrict__ WQT, const float* __restrict__ WQ_b,
    float* __restrict__ Q)
{
  __shared__ float red[4][256];
  const int c = blockIdx.x, t = threadIdx.x;
  const int d = t & 255, kk = t >> 8;
  float acc = 0.f;
  #pragma unroll 4
  for (int k = kk * 64; k < kk * 64 + 64; ++k)
    acc += Qp[c * 256 + k] * WQT[k * 256 + d];
  red[kk][d] = acc;
  __syncthreads();
  if (kk == 0)
    Q[c * 256 + d] = red[0][d] + red[1][d] + red[2][d] + red[3][d] + WQ_b[d];
}

// QW = (Q@WK)/16 (fp64 acc), QO = Q@WO^T, qb = (Q@WK_b)/16 (K split over 4)
__global__ __launch_bounds__(1024) void k_fold(const float* __restrict__ Q,
    const float* __restrict__ WK_w, const float* __restrict__ WK_b,
    const float* __restrict__ WOT,
    float* __restrict__ QW, float* __restrict__ QO, float* __restrict__ qb)
{
  __shared__ float Qrow[256];
  __shared__ double redw[4][256];
  __shared__ float redo[4][256];
  const int c = blockIdx.x, t = threadIdx.x;
  const int d = t & 255, kk = t >> 8;
  if (t < 256) Qrow[t] = Q[c * 256 + t];
  __syncthreads();
  double aqw = 0.0;
  float aqo = 0.f;
  #pragma unroll 4
  for (int j = kk * 64; j < kk * 64 + 64; ++j) {
    float qcj = Qrow[j];
    aqw += (double)qcj * (double)WK_w[j * 256 + d];   // coalesced
    aqo += qcj * WOT[j * 256 + d];                    // coalesced
  }
  redw[kk][d] = aqw;
  redo[kk][d] = aqo;
  __syncthreads();
  if (kk == 0) {
    QW[c * 256 + d] = (float)((redw[0][d] + redw[1][d] + redw[2][d] + redw[3][d]) * 0.0625);
    QO[c * 256 + d] = redo[0][d] + redo[1][d] + redo[2][d] + redo[3][d];
  }
  __syncthreads();
  if (t < 256) redw[0][t] = (double)Qrow[t] * (double)WK_b[t];
  __syncthreads();
  for (int sft = 128; sft >= 1; sft >>= 1) {
    if (t < sft) redw[0][t] += redw[0][t + sft];
    __syncthreads();
  }
  if (t == 0) qb[c] = (float)(redw[0][0] * 0.0625);
}

// Wf[i][d] = sum_j WO_w[i][j]*WV_w[j][d]; bvo[i] = sum_j WV_b[j]*WO_w[i][j]
__global__ __launch_bounds__(1024) void k_wf(const float* __restrict__ WO_w,
    const float* __restrict__ WV_w, const float* __restrict__ WV_b,
    float* __restrict__ Wf, float* __restrict__ bvo)
{
  __shared__ float red[4][256];
  __shared__ float redb[4];
  const int i = blockIdx.x, t = threadIdx.x;
  const int d = t & 255, kk = t >> 8;
  float acc = 0.f;
  #pragma unroll 4
  for (int j = kk * 64; j < kk * 64 + 64; ++j)
    acc += WO_w[i * 256 + j] * WV_w[j * 256 + d];  // WO scalar, WV coalesced
  red[kk][d] = acc;
  if (d == 0) {
    float s = 0.f;
    for (int j = kk * 64; j < kk * 64 + 64; ++j) s += WV_b[j] * WO_w[i * 256 + j];
    redb[kk] = s;
  }
  __syncthreads();
  if (kk == 0) {
    Wf[i * 256 + d] = red[0][d] + red[1][d] + red[2][d] + red[3][d];
    if (d == 0) bvo[i] = redb[0] + redb[1] + redb[2] + redb[3];
  }
}

__global__ void k_starts(const int* __restrict__ batch, int* __restrict__ starts)
{
  int t = threadIdx.x;
  if (t > 64) return;
  if (t == 0) { starts[0] = 0; return; }
  if (t == 64) { starts[64] = N_NODES; return; }
  int lo = 0, hi = N_NODES;
  while (lo < hi) {
    int mid = (lo + hi) >> 1;
    if (batch[mid] < t) lo = mid + 1; else hi = mid;
  }
  starts[t] = lo;
}

// ---------------- fused: scores + softmax + argmax/mask + G (MFMA) ----------
// grid (NP, 64 graphs), 512 threads (8 waves), chunk = 32 nodes.
// Same total work as the 256-thread round-3 version, 2x the TLP: round 3 sat
// at 8 waves/CU with VALU 39% / LDS ~42% -- dependency-bound, neither pipe
// saturated. Wave w = (wg = w&3: cluster group, wh = w>>2: half-selector).
// Waves split the h-loop (wh -> nodes 0-15 / 16-31), MFMA dt-range
// (gacc[8] = 32 AGPR, was 64), a-phase n-range, staging rows, XsT fill.
// Per-thread score k-partition and accumulation order bit-identical to
// round 3. q streamed in 16-reg quarters (same order). launch_bounds(512,4)
// -> combined regs <= 128 -> 2 blocks/CU = 16 waves/CU (4/SIMD).

__global__ __launch_bounds__(512, 4) void k_fused(
    const float* __restrict__ x, const int* __restrict__ starts,
    const float* __restrict__ qw, const float* __restrict__ qbv,
    float* __restrict__ Gp, float* __restrict__ asum,
    float* __restrict__ out_arg, float* __restrict__ out_msk)
{
  __shared__ float xs[32][256];                        // fp32 chunk, col-swizzled
  __shared__ float ss[32][68];                         // scores [n][c]
  __shared__ float stats_m[32], stats_i[32];
  __shared__ __align__(16) unsigned short As[64][40];  // a bf16 [c][n]
  __shared__ __align__(16) unsigned short XsT[256][40];// x bf16 transposed [d][n]

  const int t = threadIdx.x;
  const int p = blockIdx.x, b = blockIdx.y;
  const int s0 = starts[b], s1 = starts[b + 1];
  const int w = t >> 6, lane = t & 63;
  const int wg = w & 3, wh = w >> 2;
  const int cp = lane >> 3, kq = lane & 7;
  const int c0 = wg * 16 + cp, c1 = c0 + 8;

  const float qb0 = qbv[c0], qb1 = qbv[c1];
  const float* qg0 = qw + (size_t)c0 * 256 + kq * 16;  // thread's q slice bases
  const float* qg1 = qw + (size_t)c1 * 256 + kq * 16;

  f32x4 gacc[8];
  #pragma unroll
  for (int i = 0; i < 8; ++i) gacc[i] = (f32x4){0.f, 0.f, 0.f, 0.f};
  float asv0 = 0.f, asv1 = 0.f;

  const int stcol = (lane * 4) ^ (4 * ((lane >> 3) & 7));  // staging store column
  const int dX = t & 255, hX = t >> 8;                     // XsT-fill mapping
  const int dsz = dX ^ (4 * ((dX >> 5) & 7));              // swizzled read column

  #pragma unroll 1
  for (int base = s0 + p * 32; base < s1; base += NP * 32) {
    // ---- stage x chunk: wave w covers rows 4w..4w+3 (coalesced 1KB/row)
    #pragma unroll
    for (int i = 0; i < 4; ++i) {
      int r = w * 4 + i;
      int gr = base + r; if (gr >= s1) gr = s1 - 1;
      float4 v = *(const float4*)&x[(size_t)gr * 256 + lane * 4];
      *(float4*)&xs[r][stcol] = v;
    }
    __syncthreads();
    // ---- XsT fill: 2 threads/column; thread packs rows hX*16..hX*16+15
    #pragma unroll
    for (int g = 0; g < 4; ++g) {
      const int r0 = hX * 16 + g * 4;
      ushort4 pk;
      pk.x = f2bf(xs[r0 + 0][dsz]);
      pk.y = f2bf(xs[r0 + 1][dsz]);
      pk.z = f2bf(xs[r0 + 2][dsz]);
      pk.w = f2bf(xs[r0 + 3][dsz]);
      *(ushort4*)&XsT[dX][r0] = pk;
    }
    // ---- scores: wave-half wh covers h = 2wh..2wh+1; q streamed in quarters
    #pragma unroll 1
    for (int hh = 0; hh < 2; ++hh) {
      const int h = wh * 2 + hh;
      float a0[8], a1[8];
      #pragma unroll
      for (int n = 0; n < 8; ++n) { a0[n] = 0.f; a1[n] = 0.f; }
      const float* xb = &xs[h * 8][0];
      #pragma unroll 1
      for (int h2 = 0; h2 < 2; ++h2) {
        // first half of the k-slice (k4 = 0,1): 8 transient float4
        {
          float4 qa0 = *(const float4*)&qg0[h2 * 128 + 0];
          float4 qa1 = *(const float4*)&qg0[h2 * 128 + 4];
          float4 qc0 = *(const float4*)&qg1[h2 * 128 + 0];
          float4 qc1 = *(const float4*)&qg1[h2 * 128 + 4];
          #pragma unroll
          for (int k4 = 0; k4 < 2; ++k4) {
            const int colb = h2 * 128 + kq * 16 + k4 * 4;
            const int col = colb ^ (4 * ((colb >> 5) & 7));
            const float4 qa = k4 ? qa1 : qa0;
            const float4 qc = k4 ? qc1 : qc0;
            #pragma unroll
            for (int n = 0; n < 8; ++n) {
              float4 xv = *(const float4*)&xb[n * 256 + col];
              a0[n] = fmaf(qa.w, xv.w, fmaf(qa.z, xv.z, fmaf(qa.y, xv.y, fmaf(qa.x, xv.x, a0[n]))));
              a1[n] = fmaf(qc.w, xv.w, fmaf(qc.z, xv.z, fmaf(qc.y, xv.y, fmaf(qc.x, xv.x, a1[n]))));
            }
          }
        }
        // second half (k4 = 2,3)
        {
          float4 qa2 = *(const float4*)&qg0[h2 * 128 + 8];
          float4 qa3 = *(const float4*)&qg0[h2 * 128 + 12];
          float4 qc2 = *(const float4*)&qg1[h2 * 128 + 8];
          float4 qc3 = *(const float4*)&qg1[h2 * 128 + 12];
          #pragma unroll
          for (int k4 = 2; k4 < 4; ++k4) {
            const int colb = h2 * 128 + kq * 16 + k4 * 4;
            const int col = colb ^ (4 * ((colb >> 5) & 7));
            const float4 qa = (k4 == 2) ? qa2 : qa3;
            const float4 qc = (k4 == 2) ? qc2 : qc3;
            #pragma unroll
            for (int n = 0; n < 8; ++n) {
              float4 xv = *(const float4*)&xb[n * 256 + col];
              a0[n] = fmaf(qa.w, xv.w, fmaf(qa.z, xv.z, fmaf(qa.y, xv.y, fmaf(qa.x, xv.x, a0[n]))));
              a1[n] = fmaf(qc.w, xv.w, fmaf(qc.z, xv.z, fmaf(qc.y, xv.y, fmaf(qc.x, xv.x, a1[n]))));
            }
          }
        }
      }
      // reduce partial k-sums over kq; lane kq writes node h*8+kq
      #pragma unroll
      for (int n = 0; n < 8; ++n) {
        float s0v = kq_sum(a0[n]);
        float s1v = kq_sum(a1[n]);
        if (kq == n) {
          ss[h * 8 + n][c0] = s0v + qb0;
          ss[h * 8 + n][c1] = s1v + qb1;
        }
      }
    }
    __syncthreads();
    // ---- softmax stats + argmax: threads 0..255, 8 threads/node
    if (t < 256) {
      const int nn = t >> 3, oct = t & 7;
      float v8[8];
      #pragma unroll
      for (int u = 0; u < 8; ++u) v8[u] = ss[nn][oct * 8 + u];
      float m = v8[0]; int am = oct * 8;
      #pragma unroll
      for (int u = 1; u < 8; ++u)
        if (v8[u] > m) { m = v8[u]; am = oct * 8 + u; }   // strict >: first max
      #pragma unroll
      for (int d = 1; d < 8; d <<= 1) {
        float mo = __shfl_xor(m, d);
        int ao = __shfl_xor(am, d);
        if (mo > m || (mo == m && ao < am)) { m = mo; am = ao; }
      }
      float s = 0.f;
      #pragma unroll
      for (int u = 0; u < 8; ++u) s += __expf(v8[u] - m);
      #pragma unroll
      for (int d = 1; d < 8; d <<= 1) s += __shfl_xor(s, d);
      if (oct == 0) {
        stats_m[nn] = m;
        stats_i[nn] = 1.f / s;
        int n = base + nn;
        if (n < s1) {
          int pos = n - s0;
          out_arg[(size_t)b * MAXL + pos] = (float)am;
          out_msk[(size_t)b * MAXL + pos] = 1.0f;
        }
      }
    }
    __syncthreads();
    // ---- a-values -> As (bf16) + asum; thread covers n = 4kq+2wh+{0,1}
    {
      unsigned short pb0[2], pb1[2];
      #pragma unroll
      for (int i = 0; i < 2; ++i) {
        int nn = 4 * kq + 2 * wh + i;
        bool valid = (base + nn) < s1;
        float m = stats_m[nn], inv = stats_i[nn];
        float av0 = valid ? __expf(ss[nn][c0] - m) * inv : 0.f;
        float av1 = valid ? __expf(ss[nn][c1] - m) * inv : 0.f;
        asv0 += av0; asv1 += av1;
        pb0[i] = f2bf(av0);
        pb1[i] = f2bf(av1);
      }
      *(ushort2*)&As[c0][4 * kq + 2 * wh] = *(const ushort2*)pb0;
      *(ushort2*)&As[c1][4 * kq + 2 * wh] = *(const ushort2*)pb1;
    }
    __syncthreads();
    // ---- G MFMA: wave handles clusters 16wg..16wg+15, dt half wh*8..wh*8+7
    {
      const int q = lane >> 4, mm = lane & 15;
      bf16x8 afrag = *(const bf16x8*)&As[16 * wg + mm][q * 8];
      #pragma unroll
      for (int dt2 = 0; dt2 < 8; ++dt2) {
        const int dt = wh * 8 + dt2;
        bf16x8 bfrag = *(const bf16x8*)&XsT[16 * dt + mm][q * 8];
        gacc[dt2] = __builtin_amdgcn_mfma_f32_16x16x32_bf16(afrag, bfrag, gacc[dt2], 0, 0, 0);
      }
    }
    __syncthreads();
  }

  // ---- epilogue: store G slab (D layout: row=4*(lane>>4)+r, col=lane&15)
  {
    float* g = Gp + ((size_t)p * 64 + b) * 16384;
    const int q = lane >> 4, mm = lane & 15;
    #pragma unroll
    for (int dt2 = 0; dt2 < 8; ++dt2) {
      const int dt = wh * 8 + dt2;
      #pragma unroll
      for (int r = 0; r < 4; ++r)
        g[(size_t)(16 * wg + q * 4 + r) * 256 + 16 * dt + mm] = gacc[dt2][r];
    }
  }
  // asum: reduce per-thread partials over kq, one atomic per cluster per wh
  asv0 = kq_sum(asv0);
  asv1 = kq_sum(asv1);
  if (kq == 0) {
    atomicAdd(&asum[b * 64 + c0], asv0);
    atomicAdd(&asum[b * 64 + c1], asv1);
  }
}

// ---------------- finalize: out = relu(qo + (sum_p Gp)@Wf^T + asum*bvo + b) --

__global__ __launch_bounds__(256) void k_final(const float* __restrict__ Gp,
    int npart, const float* __restrict__ Wf, const float* __restrict__ qo,
    const float* __restrict__ asum, const float* __restrict__ bvo,
    const float* __restrict__ WO_b, float* __restrict__ out)
{
  __shared__ float gs[64 * 68];
  __shared__ float wfs[64 * 68];
  const int t = threadIdx.x;
  const int b = blockIdx.x >> 2;
  const int is = (blockIdx.x & 3) * 64;
  const int tx = t & 15, ty = t >> 4;
  const int sr = t >> 4, sq = t & 15;

  float acc[4][4];
  #pragma unroll
  for (int j = 0; j < 4; ++j)
    #pragma unroll
    for (int u = 0; u < 4; ++u) acc[j][u] = 0.f;

  for (int kc = 0; kc < 4; ++kc) {
    const int k0 = kc * 64;
    #pragma unroll
    for (int u = 0; u < 4; ++u) {
      int row = sr + 16 * u;
      float4 g = make_float4(0.f, 0.f, 0.f, 0.f);
      for (int p = 0; p < npart; ++p) {
        float4 gv = *(const float4*)&Gp[((size_t)p * 64 + b) * 16384
                                        + row * 256 + k0 + sq * 4];
        g.x += gv.x; g.y += gv.y; g.z += gv.z; g.w += gv.w;
      }
      *(float4*)&gs[row * 68 + sq * 4] = g;
      *(float4*)&wfs[row * 68 + sq * 4] =
          *(const float4*)&Wf[(size_t)(is + row) * 256 + k0 + sq * 4];
    }
    __syncthreads();
    #pragma unroll
    for (int k4 = 0; k4 < 16; ++k4) {
      float4 gr[4], wr[4];
      #pragma unroll
      for (int j = 0; j < 4; ++j) gr[j] = *(const float4*)&gs[(ty + 16 * j) * 68 + k4 * 4];
      #pragma unroll
      for (int u = 0; u < 4; ++u) wr[u] = *(const float4*)&wfs[(tx + 16 * u) * 68 + k4 * 4];
      #pragma unroll
      for (int j = 0; j < 4; ++j)
        #pragma unroll
        for (int u = 0; u < 4; ++u)
          acc[j][u] += gr[j].x * wr[u].x + gr[j].y * wr[u].y
                     + gr[j].z * wr[u].z + gr[j].w * wr[u].w;
    }
    __syncthreads();
  }

  #pragma unroll
  for (int j = 0; j < 4; ++j)
    #pragma unroll
    for (int u = 0; u < 4; ++u) {
      int cc = ty + 16 * j, i = is + tx + 16 * u;
      float v = acc[j][u] + qo[cc * 256 + i] + asum[b * 64 + cc] * bvo[i] + WO_b[i];
      out[(size_t)b * 16384 + cc * 256 + i] = fmaxf(v, 0.f);
    }
}

// ---------------- launch ----------------

extern "C" void kernel_launch(void* const* d_in, const int* in_sizes, int n_in,
                              void* d_out, int out_size, void* d_ws, size_t ws_size,
                              hipStream_t stream) {
  const float* x    = (const float*)d_in[0];
  const int*   batch= (const int*)d_in[1];
  const float* Qp   = (const float*)d_in[2];
  const float* WQ_w = (const float*)d_in[3];
  const float* WQ_b = (const float*)d_in[4];
  const float* WK_w = (const float*)d_in[5];
  const float* WK_b = (const float*)d_in[6];
  const float* WV_w = (const float*)d_in[7];
  const float* WV_b = (const float*)d_in[8];
  const float* WO_w = (const float*)d_in[9];
  const float* WO_b = (const float*)d_in[10];

  float* ws   = (float*)d_ws;
  float* QW   = ws + OFF_QW;
  float* QO   = ws + OFF_QO;
  float* Wf   = ws + OFF_WF;
  float* qb   = ws + OFF_QB;
  float* bvo  = ws + OFF_BVO;
  int*   starts = (int*)(ws + OFF_STARTS);
  float* asum = ws + OFF_ASUM;
  float* Q    = ws + OFF_Q;
  float* WQT  = ws + OFF_WQT;
  float* WOT  = ws + OFF_WOT;
  float* Gp   = ws + OFF_GP;

  float* out     = (float*)d_out;                 // [64][64][256]
  float* out_arg = out + 64 * 64 * 256;           // [64][4096]
  float* out_msk = out_arg + 64 * MAXL;           // [64][4096]

  hipMemsetAsync(asum, 0, 64 * 64 * sizeof(float), stream);
  hipMemsetAsync(out_arg, 0, (size_t)2 * 64 * MAXL * sizeof(float), stream);

  k_tr<<<dim3(8, 8, 2), 256, 0, stream>>>(WQ_w, WO_w, WQT, WOT);
  k_wf<<<256, 1024, 0, stream>>>(WO_w, WV_w, WV_b, Wf, bvo);
  k_starts<<<1, 128, 0, stream>>>(batch, starts);
  k_q<<<64, 1024, 0, stream>>>(Qp, WQT, WQ_b, Q);
  k_fold<<<64, 1024, 0, stream>>>(Q, WK_w, WK_b, WOT, QW, QO, qb);

  k_fused<<<dim3(NP, 64), 512, 0, stream>>>(x, starts, QW, qb, Gp, asum,
                                            out_arg, out_msk);
  k_final<<<64 * 4, 256, 0, stream>>>(Gp, NP, Wf, QO, asum, bvo, WO_b, out);
}

// Round 6
// 435.430 us; speedup vs baseline: 1.0351x; 1.0351x over previous
//
#include <hip/hip_runtime.h>

#define N_NODES 131072
#define MAXL 4096
#define NP 8

typedef __attribute__((ext_vector_type(8))) short bf16x8;
typedef __attribute__((ext_vector_type(4))) float f32x4;

// ws float offsets
#define OFF_QW     0u          // 64*256   folded (Q@WK)/16
#define OFF_QO     16384u      // 64*256   Q@WO^T
#define OFF_WF     32768u      // 256*256  WO@WV
#define OFF_QB     98304u      // 64
#define OFF_BVO    98368u      // 256
#define OFF_STARTS 98624u      // 65 ints (padded)
#define OFF_ASUM   98752u      // 64*64
#define OFF_Q      102848u     // 64*256
#define OFF_WQT    119232u     // 256*256
#define OFF_WOT    184768u     // 256*256
#define OFF_GP     250304u     // 8 * 64 * 16384  (end = 8638912 floats = 34.6 MB)

__device__ __forceinline__ unsigned short f2bf(float f) {
  union { float f; unsigned int u; } v; v.f = f;
  unsigned int u = v.u + 0x7FFFu + ((v.u >> 16) & 1u);  // RNE
  return (unsigned short)(u >> 16);
}

// DPP / swizzle lane-moves (value from lane^1 / lane^2 / lane^4)
__device__ __forceinline__ float dppx1(float v) {
  return __int_as_float(__builtin_amdgcn_update_dpp(0, __float_as_int(v), 0xB1, 0xF, 0xF, true));
}
__device__ __forceinline__ float dppx2(float v) {
  return __int_as_float(__builtin_amdgcn_update_dpp(0, __float_as_int(v), 0x4E, 0xF, 0xF, true));
}
__device__ __forceinline__ float swzx4(float v) {
  return __int_as_float(__builtin_amdgcn_ds_swizzle(__float_as_int(v), 0x101F));
}
// full butterfly sum over kq (used for asum only)
__device__ __forceinline__ float kq_sum(float v) {
  v += dppx1(v); v += dppx2(v); v += swzx4(v); return v;
}
// staged merge: keep one of (u=bit0,v=bit1) by sel, add partner's other
__device__ __forceinline__ float mrg1(float u, float v, bool sel) {
  float snd = sel ? u : v, kp = sel ? v : u; return kp + dppx1(snd);
}
__device__ __forceinline__ float mrg2(float u, float v, bool sel) {
  float snd = sel ? u : v, kp = sel ? v : u; return kp + dppx2(snd);
}
__device__ __forceinline__ float mrg4(float u, float v, bool sel) {
  float snd = sel ? u : v, kp = sel ? v : u; return kp + swzx4(snd);
}

// ---------------- setup ----------------

// transpose WQ_w (z=0) and WO_w (z=1) into WQT / WOT
__global__ __launch_bounds__(256) void k_tr(const float* __restrict__ WQ_w,
    const float* __restrict__ WO_w, float* __restrict__ WQT, float* __restrict__ WOT)
{
  __shared__ float tile[32][33];
  const float* src = blockIdx.z ? WO_w : WQ_w;
  float* dst = blockIdx.z ? WOT : WQT;
  const int bx = blockIdx.x * 32, by = blockIdx.y * 32;
  const int tx = threadIdx.x & 31, ty = threadIdx.x >> 5;
  #pragma unroll
  for (int i = 0; i < 4; ++i)
    tile[ty + 8 * i][tx] = src[(size_t)(by + ty + 8 * i) * 256 + bx + tx];
  __syncthreads();
  #pragma unroll
  for (int i = 0; i < 4; ++i)
    dst[(size_t)(bx + ty + 8 * i) * 256 + by + tx] = tile[tx][ty + 8 * i];
}

// Q[c][d] = sum_k Qp[c][k] * WQT[k][d] + WQ_b[d]   (K split over 4 groups)
__global__ __launch_bounds__(1024) void k_q(const float* __restrict__ Qp,
    const float* __restrict__ WQT, const float* __restrict__ WQ_b,
    float* __restrict__ Q)
{
  __shared__ float red[4][256];
  const int c = blockIdx.x, t = threadIdx.x;
  const int d = t & 255, kk = t >> 8;
  float acc = 0.f;
  #pragma unroll 4
  for (int k = kk * 64; k < kk * 64 + 64; ++k)
    acc += Qp[c * 256 + k] * WQT[k * 256 + d];
  red[kk][d] = acc;
  __syncthreads();
  if (kk == 0)
    Q[c * 256 + d] = red[0][d] + red[1][d] + red[2][d] + red[3][d] + WQ_b[d];
}

// QW = (Q@WK)/16 (fp64 acc), QO = Q@WO^T, qb = (Q@WK_b)/16 (K split over 4)
__global__ __launch_bounds__(1024) void k_fold(const float* __restrict__ Q,
    const float* __restrict__ WK_w, const float* __restrict__ WK_b,
    const float* __restrict__ WOT,
    float* __restrict__ QW, float* __restrict__ QO, float* __restrict__ qb)
{
  __shared__ float Qrow[256];
  __shared__ double redw[4][256];
  __shared__ float redo[4][256];
  const int c = blockIdx.x, t = threadIdx.x;
  const int d = t & 255, kk = t >> 8;
  if (t < 256) Qrow[t] = Q[c * 256 + t];
  __syncthreads();
  double aqw = 0.0;
  float aqo = 0.f;
  #pragma unroll 4
  for (int j = kk * 64; j < kk * 64 + 64; ++j) {
    float qcj = Qrow[j];
    aqw += (double)qcj * (double)WK_w[j * 256 + d];   // coalesced
    aqo += qcj * WOT[j * 256 + d];                    // coalesced
  }
  redw[kk][d] = aqw;
  redo[kk][d] = aqo;
  __syncthreads();
  if (kk == 0) {
    QW[c * 256 + d] = (float)((redw[0][d] + redw[1][d] + redw[2][d] + redw[3][d]) * 0.0625);
    QO[c * 256 + d] = redo[0][d] + redo[1][d] + redo[2][d] + redo[3][d];
  }
  __syncthreads();
  if (t < 256) redw[0][t] = (double)Qrow[t] * (double)WK_b[t];
  __syncthreads();
  for (int sft = 128; sft >= 1; sft >>= 1) {
    if (t < sft) redw[0][t] += redw[0][t + sft];
    __syncthreads();
  }
  if (t == 0) qb[c] = (float)(redw[0][0] * 0.0625);
}

// Wf[i][d] = sum_j WO_w[i][j]*WV_w[j][d]; bvo[i] = sum_j WV_b[j]*WO_w[i][j]
__global__ __launch_bounds__(1024) void k_wf(const float* __restrict__ WO_w,
    const float* __restrict__ WV_w, const float* __restrict__ WV_b,
    float* __restrict__ Wf, float* __restrict__ bvo)
{
  __shared__ float red[4][256];
  __shared__ float redb[4];
  const int i = blockIdx.x, t = threadIdx.x;
  const int d = t & 255, kk = t >> 8;
  float acc = 0.f;
  #pragma unroll 4
  for (int j = kk * 64; j < kk * 64 + 64; ++j)
    acc += WO_w[i * 256 + j] * WV_w[j * 256 + d];  // WO scalar, WV coalesced
  red[kk][d] = acc;
  if (d == 0) {
    float s = 0.f;
    for (int j = kk * 64; j < kk * 64 + 64; ++j) s += WV_b[j] * WO_w[i * 256 + j];
    redb[kk] = s;
  }
  __syncthreads();
  if (kk == 0) {
    Wf[i * 256 + d] = red[0][d] + red[1][d] + red[2][d] + red[3][d];
    if (d == 0) bvo[i] = redb[0] + redb[1] + redb[2] + redb[3];
  }
}

__global__ void k_starts(const int* __restrict__ batch, int* __restrict__ starts)
{
  int t = threadIdx.x;
  if (t > 64) return;
  if (t == 0) { starts[0] = 0; return; }
  if (t == 64) { starts[64] = N_NODES; return; }
  int lo = 0, hi = N_NODES;
  while (lo < hi) {
    int mid = (lo + hi) >> 1;
    if (batch[mid] < t) lo = mid + 1; else hi = mid;
  }
  starts[t] = lo;
}

// ---------------- fused: scores + softmax + argmax/mask + G (MFMA) ----------
// grid (NP, 64 graphs), 512 threads (8 waves), chunk = 32 nodes.
// Round-5 structure with the ss-row bug fixed: wave-half wh computes nodes
// wh*16 + nb*4 + n, and the staged-merge result MUST be written to row
// wh*16 + nb*4 + (kq&3) (round 5 dropped the wh*16 -> rows 16-31 stale,
// absmax 101). Staged pair-reduce verified lane-by-lane: lane kq ends with
// the 8-lane k-sum for (cluster = kq&4 ? c1 : c0, node = kq&3 of sub-block).
// Register diet: node sub-blocks of 4 (acc 8 regs, xv 16), q in 16-reg
// transient batches. Peak live ~75 arch + 32 AGPR -> fits 4 waves/SIMD.

__global__ __launch_bounds__(512, 4) void k_fused(
    const float* __restrict__ x, const int* __restrict__ starts,
    const float* __restrict__ qw, const float* __restrict__ qbv,
    float* __restrict__ Gp, float* __restrict__ asum,
    float* __restrict__ out_arg, float* __restrict__ out_msk)
{
  __shared__ float xs[32][256];                        // fp32 chunk, col-swizzled
  __shared__ float ss[32][68];                         // scores [n][c]
  __shared__ float stats_m[32], stats_i[32];
  __shared__ __align__(16) unsigned short As[64][40];  // a bf16 [c][n]
  __shared__ __align__(16) unsigned short XsT[256][40];// x bf16 transposed [d][n]

  const int t = threadIdx.x;
  const int p = blockIdx.x, b = blockIdx.y;
  const int s0 = starts[b], s1 = starts[b + 1];
  const int w = t >> 6, lane = t & 63;
  const int wg = w & 3, wh = w >> 2;
  const int cp = lane >> 3, kq = lane & 7;
  const int c0 = wg * 16 + cp, c1 = c0 + 8;

  const float qb0 = qbv[c0], qb1 = qbv[c1];
  const float* qg0 = qw + (size_t)c0 * 256 + kq * 16;  // thread's q slice bases
  const float* qg1 = qw + (size_t)c1 * 256 + kq * 16;

  f32x4 gacc[8];
  #pragma unroll
  for (int i = 0; i < 8; ++i) gacc[i] = (f32x4){0.f, 0.f, 0.f, 0.f};
  float asv0 = 0.f, asv1 = 0.f;

  const bool sel1 = (kq & 1), sel2 = (kq & 2), sel4 = (kq & 4);
  const int stcol = (lane * 4) ^ (4 * ((lane >> 3) & 7));  // staging store column
  const int dX = t & 255, hX = t >> 8;                     // XsT-fill mapping
  const int dsz = dX ^ (4 * ((dX >> 5) & 7));              // swizzled read column

  #pragma unroll 1
  for (int base = s0 + p * 32; base < s1; base += NP * 32) {
    // ---- stage x chunk: wave w covers rows 4w..4w+3 (coalesced 1KB/row)
    #pragma unroll
    for (int i = 0; i < 4; ++i) {
      int r = w * 4 + i;
      int gr = base + r; if (gr >= s1) gr = s1 - 1;
      float4 v = *(const float4*)&x[(size_t)gr * 256 + lane * 4];
      *(float4*)&xs[r][stcol] = v;
    }
    __syncthreads();
    // ---- XsT fill: 2 threads/column; thread packs rows hX*16..hX*16+15
    #pragma unroll
    for (int g = 0; g < 4; ++g) {
      const int r0 = hX * 16 + g * 4;
      ushort4 pk;
      pk.x = f2bf(xs[r0 + 0][dsz]);
      pk.y = f2bf(xs[r0 + 1][dsz]);
      pk.z = f2bf(xs[r0 + 2][dsz]);
      pk.w = f2bf(xs[r0 + 3][dsz]);
      *(ushort4*)&XsT[dX][r0] = pk;
    }
    // ---- scores: wave-half wh covers nodes wh*16..wh*16+15, 4 sub-blocks of 4
    #pragma unroll 1
    for (int nb = 0; nb < 4; ++nb) {
      float a0[4], a1[4];
      #pragma unroll
      for (int n = 0; n < 4; ++n) { a0[n] = 0.f; a1[n] = 0.f; }
      const float* xb = &xs[wh * 16 + nb * 4][0];
      #pragma unroll 1
      for (int h2 = 0; h2 < 2; ++h2) {
        // k4 = 0,1: 8 transient q regs per cluster pair
        {
          float4 qa0 = *(const float4*)&qg0[h2 * 128 + 0];
          float4 qa1 = *(const float4*)&qg0[h2 * 128 + 4];
          float4 qc0 = *(const float4*)&qg1[h2 * 128 + 0];
          float4 qc1 = *(const float4*)&qg1[h2 * 128 + 4];
          #pragma unroll
          for (int k4 = 0; k4 < 2; ++k4) {
            const int colb = h2 * 128 + kq * 16 + k4 * 4;
            const int col = colb ^ (4 * ((colb >> 5) & 7));
            const float4 qa = k4 ? qa1 : qa0;
            const float4 qc = k4 ? qc1 : qc0;
            #pragma unroll
            for (int n = 0; n < 4; ++n) {
              float4 xv = *(const float4*)&xb[n * 256 + col];
              a0[n] = fmaf(qa.w, xv.w, fmaf(qa.z, xv.z, fmaf(qa.y, xv.y, fmaf(qa.x, xv.x, a0[n]))));
              a1[n] = fmaf(qc.w, xv.w, fmaf(qc.z, xv.z, fmaf(qc.y, xv.y, fmaf(qc.x, xv.x, a1[n]))));
            }
          }
        }
        // k4 = 2,3
        {
          float4 qa2 = *(const float4*)&qg0[h2 * 128 + 8];
          float4 qa3 = *(const float4*)&qg0[h2 * 128 + 12];
          float4 qc2 = *(const float4*)&qg1[h2 * 128 + 8];
          float4 qc3 = *(const float4*)&qg1[h2 * 128 + 12];
          #pragma unroll
          for (int k4 = 2; k4 < 4; ++k4) {
            const int colb = h2 * 128 + kq * 16 + k4 * 4;
            const int col = colb ^ (4 * ((colb >> 5) & 7));
            const float4 qa = (k4 == 2) ? qa2 : qa3;
            const float4 qc = (k4 == 2) ? qc2 : qc3;
            #pragma unroll
            for (int n = 0; n < 4; ++n) {
              float4 xv = *(const float4*)&xb[n * 256 + col];
              a0[n] = fmaf(qa.w, xv.w, fmaf(qa.z, xv.z, fmaf(qa.y, xv.y, fmaf(qa.x, xv.x, a0[n]))));
              a1[n] = fmaf(qc.w, xv.w, fmaf(qc.z, xv.z, fmaf(qc.y, xv.y, fmaf(qc.x, xv.x, a1[n]))));
            }
          }
        }
      }
      // staged reduce over kq: xor1 resolves n bit0, xor2 n bit1, xor4 cluster.
      // Lane kq ends with (c = kq&4 ? c1 : c0, node = wh*16 + nb*4 + (kq&3)).
      {
        float r00 = mrg1(a0[0], a0[1], sel1);
        float r01 = mrg1(a0[2], a0[3], sel1);
        float r10 = mrg1(a1[0], a1[1], sel1);
        float r11 = mrg1(a1[2], a1[3], sel1);
        float t0  = mrg2(r00, r01, sel2);
        float t1  = mrg2(r10, r11, sel2);
        float val = mrg4(t0, t1, sel4);
        const int nn = wh * 16 + nb * 4 + (kq & 3);   // FIX: include wh*16
        ss[nn][sel4 ? c1 : c0] = val + (sel4 ? qb1 : qb0);
      }
    }
    __syncthreads();
    // ---- softmax stats + argmax: threads 0..255, 8 threads/node
    if (t < 256) {
      const int nn = t >> 3, oct = t & 7;
      float v8[8];
      #pragma unroll
      for (int u = 0; u < 8; ++u) v8[u] = ss[nn][oct * 8 + u];
      float m = v8[0]; int am = oct * 8;
      #pragma unroll
      for (int u = 1; u < 8; ++u)
        if (v8[u] > m) { m = v8[u]; am = oct * 8 + u; }   // strict >: first max
      #pragma unroll
      for (int d = 1; d < 8; d <<= 1) {
        float mo = __shfl_xor(m, d);
        int ao = __shfl_xor(am, d);
        if (mo > m || (mo == m && ao < am)) { m = mo; am = ao; }
      }
      float s = 0.f;
      #pragma unroll
      for (int u = 0; u < 8; ++u) s += __expf(v8[u] - m);
      #pragma unroll
      for (int d = 1; d < 8; d <<= 1) s += __shfl_xor(s, d);
      if (oct == 0) {
        stats_m[nn] = m;
        stats_i[nn] = 1.f / s;
        int n = base + nn;
        if (n < s1) {
          int pos = n - s0;
          out_arg[(size_t)b * MAXL + pos] = (float)am;
          out_msk[(size_t)b * MAXL + pos] = 1.0f;
        }
      }
    }
    __syncthreads();
    // ---- a-values -> As (bf16) + asum; thread covers n = 4kq+2wh+{0,1}
    {
      unsigned short pb0[2], pb1[2];
      #pragma unroll
      for (int i = 0; i < 2; ++i) {
        int nn = 4 * kq + 2 * wh + i;
        bool valid = (base + nn) < s1;
        float m = stats_m[nn], inv = stats_i[nn];
        float av0 = valid ? __expf(ss[nn][c0] - m) * inv : 0.f;
        float av1 = valid ? __expf(ss[nn][c1] - m) * inv : 0.f;
        asv0 += av0; asv1 += av1;
        pb0[i] = f2bf(av0);
        pb1[i] = f2bf(av1);
      }
      *(ushort2*)&As[c0][4 * kq + 2 * wh] = *(const ushort2*)pb0;
      *(ushort2*)&As[c1][4 * kq + 2 * wh] = *(const ushort2*)pb1;
    }
    __syncthreads();
    // ---- G MFMA: wave handles clusters 16wg..16wg+15, dt half wh*8..wh*8+7
    {
      const int q = lane >> 4, mm = lane & 15;
      bf16x8 afrag = *(const bf16x8*)&As[16 * wg + mm][q * 8];
      #pragma unroll
      for (int dt2 = 0; dt2 < 8; ++dt2) {
        const int dt = wh * 8 + dt2;
        bf16x8 bfrag = *(const bf16x8*)&XsT[16 * dt + mm][q * 8];
        gacc[dt2] = __builtin_amdgcn_mfma_f32_16x16x32_bf16(afrag, bfrag, gacc[dt2], 0, 0, 0);
      }
    }
    __syncthreads();
  }

  // ---- epilogue: store G slab (D layout: row=4*(lane>>4)+r, col=lane&15)
  {
    float* g = Gp + ((size_t)p * 64 + b) * 16384;
    const int q = lane >> 4, mm = lane & 15;
    #pragma unroll
    for (int dt2 = 0; dt2 < 8; ++dt2) {
      const int dt = wh * 8 + dt2;
      #pragma unroll
      for (int r = 0; r < 4; ++r)
        g[(size_t)(16 * wg + q * 4 + r) * 256 + 16 * dt + mm] = gacc[dt2][r];
    }
  }
  // asum: reduce per-thread partials over kq, one atomic per cluster per wh
  asv0 = kq_sum(asv0);
  asv1 = kq_sum(asv1);
  if (kq == 0) {
    atomicAdd(&asum[b * 64 + c0], asv0);
    atomicAdd(&asum[b * 64 + c1], asv1);
  }
}

// ---------------- finalize: out = relu(qo + (sum_p Gp)@Wf^T + asum*bvo + b) --

__global__ __launch_bounds__(256) void k_final(const float* __restrict__ Gp,
    int npart, const float* __restrict__ Wf, const float* __restrict__ qo,
    const float* __restrict__ asum, const float* __restrict__ bvo,
    const float* __restrict__ WO_b, float* __restrict__ out)
{
  __shared__ float gs[64 * 68];
  __shared__ float wfs[64 * 68];
  const int t = threadIdx.x;
  const int b = blockIdx.x >> 2;
  const int is = (blockIdx.x & 3) * 64;
  const int tx = t & 15, ty = t >> 4;
  const int sr = t >> 4, sq = t & 15;

  float acc[4][4];
  #pragma unroll
  for (int j = 0; j < 4; ++j)
    #pragma unroll
    for (int u = 0; u < 4; ++u) acc[j][u] = 0.f;

  for (int kc = 0; kc < 4; ++kc) {
    const int k0 = kc * 64;
    #pragma unroll
    for (int u = 0; u < 4; ++u) {
      int row = sr + 16 * u;
      float4 g = make_float4(0.f, 0.f, 0.f, 0.f);
      for (int p = 0; p < npart; ++p) {
        float4 gv = *(const float4*)&Gp[((size_t)p * 64 + b) * 16384
                                        + row * 256 + k0 + sq * 4];
        g.x += gv.x; g.y += gv.y; g.z += gv.z; g.w += gv.w;
      }
      *(float4*)&gs[row * 68 + sq * 4] = g;
      *(float4*)&wfs[row * 68 + sq * 4] =
          *(const float4*)&Wf[(size_t)(is + row) * 256 + k0 + sq * 4];
    }
    __syncthreads();
    #pragma unroll
    for (int k4 = 0; k4 < 16; ++k4) {
      float4 gr[4], wr[4];
      #pragma unroll
      for (int j = 0; j < 4; ++j) gr[j] = *(const float4*)&gs[(ty + 16 * j) * 68 + k4 * 4];
      #pragma unroll
      for (int u = 0; u < 4; ++u) wr[u] = *(const float4*)&wfs[(tx + 16 * u) * 68 + k4 * 4];
      #pragma unroll
      for (int j = 0; j < 4; ++j)
        #pragma unroll
        for (int u = 0; u < 4; ++u)
          acc[j][u] += gr[j].x * wr[u].x + gr[j].y * wr[u].y
                     + gr[j].z * wr[u].z + gr[j].w * wr[u].w;
    }
    __syncthreads();
  }

  #pragma unroll
  for (int j = 0; j < 4; ++j)
    #pragma unroll
    for (int u = 0; u < 4; ++u) {
      int cc = ty + 16 * j, i = is + tx + 16 * u;
      float v = acc[j][u] + qo[cc * 256 + i] + asum[b * 64 + cc] * bvo[i] + WO_b[i];
      out[(size_t)b * 16384 + cc * 256 + i] = fmaxf(v, 0.f);
    }
}

// ---------------- launch ----------------

extern "C" void kernel_launch(void* const* d_in, const int* in_sizes, int n_in,
                              void* d_out, int out_size, void* d_ws, size_t ws_size,
                              hipStream_t stream) {
  const float* x    = (const float*)d_in[0];
  const int*   batch= (const int*)d_in[1];
  const float* Qp   = (const float*)d_in[2];
  const float* WQ_w = (const float*)d_in[3];
  const float* WQ_b = (const float*)d_in[4];
  const float* WK_w = (const float*)d_in[5];
  const float* WK_b = (const float*)d_in[6];
  const float* WV_w = (const float*)d_in[7];
  const float* WV_b = (const float*)d_in[8];
  const float* WO_w = (const float*)d_in[9];
  const float* WO_b = (const float*)d_in[10];

  float* ws   = (float*)d_ws;
  float* QW   = ws + OFF_QW;
  float* QO   = ws + OFF_QO;
  float* Wf   = ws + OFF_WF;
  float* qb   = ws + OFF_QB;
  float* bvo  = ws + OFF_BVO;
  int*   starts = (int*)(ws + OFF_STARTS);
  float* asum = ws + OFF_ASUM;
  float* Q    = ws + OFF_Q;
  float* WQT  = ws + OFF_WQT;
  float* WOT  = ws + OFF_WOT;
  float* Gp   = ws + OFF_GP;

  float* out     = (float*)d_out;                 // [64][64][256]
  float* out_arg = out + 64 * 64 * 256;           // [64][4096]
  float* out_msk = out_arg + 64 * MAXL;           // [64][4096]

  hipMemsetAsync(asum, 0, 64 * 64 * sizeof(float), stream);
  hipMemsetAsync(out_arg, 0, (size_t)2 * 64 * MAXL * sizeof(float), stream);

  k_tr<<<dim3(8, 8, 2), 256, 0, stream>>>(WQ_w, WO_w, WQT, WOT);
  k_wf<<<256, 1024, 0, stream>>>(WO_w, WV_w, WV_b, Wf, bvo);
  k_starts<<<1, 128, 0, stream>>>(batch, starts);
  k_q<<<64, 1024, 0, stream>>>(Qp, WQT, WQ_b, Q);
  k_fold<<<64, 1024, 0, stream>>>(Q, WK_w, WK_b, WOT, QW, QO, qb);

  k_fused<<<dim3(NP, 64), 512, 0, stream>>>(x, starts, QW, qb, Gp, asum,
                                            out_arg, out_msk);
  k_final<<<64 * 4, 256, 0, stream>>>(Gp, NP, Wf, QO, asum, bvo, WO_b, out);
}